// Round 5
// baseline (265.690 us; speedup 1.0000x reference)
//
#include <hip/hip_runtime.h>
#include <math.h>

#define B_    16
#define M_    128
#define T_    2048
#define H_    512
#define TOUT_ 2049

typedef unsigned short u16;
typedef unsigned int   u32;
typedef __bf16 bf16x8 __attribute__((ext_vector_type(8)));
typedef float  f32x16 __attribute__((ext_vector_type(16)));
typedef u32    u32x4  __attribute__((ext_vector_type(4)));
typedef u32    u32x2  __attribute__((ext_vector_type(2)));

// ws layout (float units):
#define A_OFF     0                       // fp32 Ao only [128][128]
#define C_OFF     16384                   // c[3][128]
#define MEAN_OFF  16896                   // meanv [2048]
#define AQKBF_OFF 19200                   // u16 [256][128] = 16384 fl
#define AOBF_OFF  35584                   // u16 [128][128] = 8192 fl
#define QT_OFF    43776
#define KT_OFF    (43776 + 2097152)
#define VB_OFF    (43776 + 2 * 2097152)

static __device__ __forceinline__ u16 f2bf(float f) {
  u32 u = __float_as_uint(f);
  u = (u + 0x7FFFu + ((u >> 16) & 1u)) >> 16;
  return (u16)u;
}
static __device__ __forceinline__ u32 pk2(float lo, float hi) {
  return (u32)f2bf(lo) | ((u32)f2bf(hi) << 16);
}
static __device__ __forceinline__ bf16x8 ldfrag(const u16* p) {
  return __builtin_bit_cast(bf16x8, *(const u32x4*)p);
}

// ---------------------------------------------------------------------------
__global__ __launch_bounds__(128) void fuse_weights_all(
    const float* __restrict__ W1q, const float* __restrict__ b1q,
    const float* __restrict__ W2q, const float* __restrict__ b2q,
    const float* __restrict__ W1k, const float* __restrict__ b1k,
    const float* __restrict__ W2k, const float* __restrict__ b2k,
    const float* __restrict__ W1o, const float* __restrict__ b1o,
    const float* __restrict__ W2o, const float* __restrict__ b2o,
    float* __restrict__ A, float* __restrict__ c,
    u16* __restrict__ Aqk_bf, u16* __restrict__ Ao_bf) {
  __shared__ float w2row[H_];
  int which = blockIdx.x >> 7;
  int o = blockIdx.x & 127;
  const float* W1 = which == 0 ? W1q : which == 1 ? W1k : W1o;
  const float* b1 = which == 0 ? b1q : which == 1 ? b1k : b1o;
  const float* W2 = which == 0 ? W2q : which == 1 ? W2k : W2o;
  const float* b2 = which == 0 ? b2q : which == 1 ? b2k : b2o;
  int m = threadIdx.x;
  for (int h = m; h < H_; h += 128) w2row[h] = W2[o * H_ + h];
  __syncthreads();
  float acc = 0.f;
#pragma unroll 8
  for (int h = 0; h < H_; ++h) acc = fmaf(w2row[h], W1[h * M_ + m], acc);
  u16 ab = f2bf(acc);
  if (which == 0)      Aqk_bf[o * 128 + m] = ab;
  else if (which == 1) Aqk_bf[(128 + o) * 128 + m] = ab;
  else               { Ao_bf[o * 128 + m] = ab; A[o * M_ + m] = acc; }
  // bias fusion: parallel across one wave + shuffle reduce
  if (m < 64) {
    float cc = 0.f;
    for (int h = m; h < H_; h += 64) cc = fmaf(w2row[h], b1[h], cc);
#pragma unroll
    for (int off = 32; off > 0; off >>= 1) cc += __shfl_down(cc, off, 64);
    if (m == 0) c[which * 128 + o] = cc + b2[o];
  }
}

// ---------------------------------------------------------------------------
// prep: blocks [0,512) = q/k MLP (MFMA, coalesced I/O);
//       blocks [512,2560) = value cast + windowed mean
#define XS 68    // f32 stride of staged pattern [128][68]

__global__ __launch_bounds__(256) void prep_kernel(
    const float* __restrict__ pattern, const u16* __restrict__ Aqk_bf,
    const float* __restrict__ cqk, u16* __restrict__ qT, u16* __restrict__ kT,
    const float* __restrict__ value, u16* __restrict__ vb,
    float* __restrict__ meanv) {
  __shared__ alignas(16) float xsf[128 * XS];  // 34816 B; reused as obuf u16[64][258]
  int bx = blockIdx.x;
  int tid = threadIdx.x;

  if (bx >= 512) {
    // ---- value cast + windowed mean
    int bm = bx - 512;
    float* red = xsf;
    const float* row = value + (size_t)bm * T_;
    int i0 = tid * 8;
    float4 a = *(const float4*)(row + i0);
    float4 bq = *(const float4*)(row + i0 + 4);
    u32x4 o = {pk2(a.x, a.y), pk2(a.z, a.w), pk2(bq.x, bq.y), pk2(bq.z, bq.w)};
    *(u32x4*)&vb[(size_t)bm * T_ + i0] = o;
    float vals[8] = {a.x, a.y, a.z, a.w, bq.x, bq.y, bq.z, bq.w};
    float s = 0.f;
#pragma unroll
    for (int j = 0; j < 8; ++j) {
      int idx = i0 + j;
      if (idx >= 33 && idx < T_ - 1) s += vals[j];
    }
    red[tid] = s;
    __syncthreads();
    for (int st = 128; st > 0; st >>= 1) {
      if (tid < st) red[tid] += red[tid + st];
      __syncthreads();
    }
    if (tid == 0) meanv[bm] = red[0] * (1.f / 2014.f);
    return;
  }

  int b = bx >> 5;
  int t0 = (bx & 31) * 64;
  int lane = tid & 63;
  int wv = tid >> 6;
  int l31 = lane & 31;
  int lh8 = (lane >> 5) * 8;

  // A-frags: wave handles o-tiles {2wv, 2wv+1} of 8 (q:0-3, k:4-7)
  bf16x8 afr[2][8];
#pragma unroll
  for (int i = 0; i < 2; ++i) {
    const u16* ap = Aqk_bf + ((2 * wv + i) * 32 + l31) * 128 + lh8;
#pragma unroll
    for (int s = 0; s < 8; ++s) afr[i][s] = ldfrag(ap + 16 * s);
  }

  // stage pattern [128 m][64 t] f32, fully coalesced
#pragma unroll
  for (int rep = 0; rep < 8; ++rep) {
    int m = rep * 16 + (tid >> 4);
    int tc = (tid & 15) * 4;
    float4 v = *(const float4*)&pattern[(size_t)(b * M_ + m) * T_ + t0 + tc];
    *(float4*)&xsf[m * XS + tc] = v;
  }
  __syncthreads();

  // all 16 B-frags via conflict-free strided b32 reads + bf16 pack
  bf16x8 bfr[2][8];
#pragma unroll
  for (int tt = 0; tt < 2; ++tt) {
#pragma unroll
    for (int s = 0; s < 8; ++s) {
      float v0 = xsf[(s * 16 + lh8 + 0) * XS + tt * 32 + l31];
      float v1 = xsf[(s * 16 + lh8 + 1) * XS + tt * 32 + l31];
      float v2 = xsf[(s * 16 + lh8 + 2) * XS + tt * 32 + l31];
      float v3 = xsf[(s * 16 + lh8 + 3) * XS + tt * 32 + l31];
      float v4 = xsf[(s * 16 + lh8 + 4) * XS + tt * 32 + l31];
      float v5 = xsf[(s * 16 + lh8 + 5) * XS + tt * 32 + l31];
      float v6 = xsf[(s * 16 + lh8 + 6) * XS + tt * 32 + l31];
      float v7 = xsf[(s * 16 + lh8 + 7) * XS + tt * 32 + l31];
      u32x4 p = {pk2(v0, v1), pk2(v2, v3), pk2(v4, v5), pk2(v6, v7)};
      bfr[tt][s] = __builtin_bit_cast(bf16x8, p);
    }
  }
  __syncthreads();  // xsf dead -> obuf

  u16* obuf = (u16*)xsf;  // [64 t][258 o]  (word-stride 129 == +1 bank)
#pragma unroll
  for (int tt = 0; tt < 2; ++tt) {
#pragma unroll
    for (int i = 0; i < 2; ++i) {
      f32x16 acc;
#pragma unroll
      for (int r = 0; r < 16; ++r) acc[r] = 0.f;
#pragma unroll
      for (int s = 0; s < 8; ++s)
        acc = __builtin_amdgcn_mfma_f32_32x32x16_bf16(afr[i][s], bfr[tt][s], acc, 0, 0, 0);
      int ot = 2 * wv + i;
      int t = tt * 32 + l31;
#pragma unroll
      for (int r = 0; r < 16; ++r) {
        int orow = (r & 3) + 8 * (r >> 2) + 4 * (lane >> 5);
        float v = acc[r] + cqk[ot * 32 + orow];
        v = v > 0.f ? v : 0.01f * v;
        obuf[t * 258 + ot * 32 + orow] = f2bf(v);
      }
    }
  }
  __syncthreads();

  // coalesced store: 1 KB contiguous per instruction
  const u32* ob32 = (const u32*)obuf;
#pragma unroll
  for (int g = 0; g < 8; ++g) {
    int G = wv * 8 + g;               // [0,32)
    int mat = G >> 4;                 // 0=q, 1=k
    int t = (G & 15) * 4 + (lane >> 4);
    int og2 = lane & 15;
    int wbase = t * 129 + mat * 64 + og2 * 4;
    u32x4 vv = {ob32[wbase], ob32[wbase + 1], ob32[wbase + 2], ob32[wbase + 3]};
    u32* dst = (u32*)((mat ? kT : qT) + ((size_t)(b * T_ + t0 + t)) * 128) + og2 * 4;
    *(u32x4*)dst = vv;
  }
}

// ---------------------------------------------------------------------------
// attn v3: K/V direct global->register frags, wsm-only in-loop LDS,
// fused o-MLP epilogue + rep_ex tail.
#define QSTR 136  // u16: 68 words == 4 mod 32
#define VSTR 72   // u16: 36 words == 4 mod 32

__global__ __launch_bounds__(256, 2) void attn_mfma_kernel(
    const u16* __restrict__ qT, const u16* __restrict__ kT,
    const u16* __restrict__ vB, const u16* __restrict__ Ao_bf,
    const float* __restrict__ co, const float* __restrict__ Aofp,
    const float* __restrict__ meanv, float* __restrict__ out) {
  __shared__ alignas(16) u16 qsw[64 * QSTR];  // Q stage -> P^T [q][m]
  __shared__ alignas(16) u16 wsm[64 * VSTR];  // [q][k]
  __shared__ float dls[128];

  int b = blockIdx.y;
  int q0 = blockIdx.x * 64;
  int tid = threadIdx.x;
  int lane = tid & 63;
  int wv = tid >> 6;
  int l31 = lane & 31;
  int lh8 = (lane >> 5) * 8;

  // stage Q tile (coalesced) and load persistent A-frags
  {
    const u16* gq = qT + (size_t)(b * T_ + q0) * 128;
#pragma unroll
    for (int it = 0; it < 4; ++it) {
      int r = it * 16 + (tid >> 4);
      int cm = (tid & 15) * 8;
      *(u32x4*)&qsw[r * QSTR + cm] = *(const u32x4*)&gq[r * 128 + cm];
    }
  }
  __syncthreads();

  int qw = (wv >> 1) * 32;   // S-phase q-half
  int kw = (wv & 1) * 32;    // S-phase k-half
  bf16x8 afrag[8];
  {
    const u16* qrow = &qsw[(qw + l31) * QSTR + lh8];
#pragma unroll
    for (int s = 0; s < 8; ++s) afrag[s] = ldfrag(qrow + s * 16);
  }

  int qt = wv & 1;           // PV q-tile
  int mb = (wv >> 1) * 2;    // PV m-tile base

  // global frag base pointers
  const u16* kbase  = kT + ((size_t)(b * T_ + kw + l31)) * 128 + lh8;
  const u16* vbase0 = vB + ((size_t)(b * M_ + mb * 32 + l31)) * T_ + lh8;
  const u16* vbase1 = vB + ((size_t)(b * M_ + (mb + 1) * 32 + l31)) * T_ + lh8;

  f32x16 pacc[2];
  float dreg[16];
#pragma unroll
  for (int i = 0; i < 16; ++i) { pacc[0][i] = 0.f; pacc[1][i] = 0.f; dreg[i] = 0.f; }

  bf16x8 kf[8], vf[8];
  // prologue: K frags for tile 0
#pragma unroll
  for (int s = 0; s < 8; ++s) kf[s] = ldfrag(kbase + s * 16);

#pragma unroll 1
  for (int kt = 0; kt < T_ / 64; ++kt) {
    int k0 = kt * 64;
    // V frags for this tile (consumed in PV, hidden under S+exp)
#pragma unroll
    for (int s2 = 0; s2 < 4; ++s2) {
      vf[s2]     = ldfrag(vbase0 + k0 + s2 * 16);
      vf[4 + s2] = ldfrag(vbase1 + k0 + s2 * 16);
    }

    // S = Q^T K
    f32x16 sacc;
#pragma unroll
    for (int i = 0; i < 16; ++i) sacc[i] = 0.f;
#pragma unroll
    for (int s = 0; s < 8; ++s)
      sacc = __builtin_amdgcn_mfma_f32_32x32x16_bf16(afrag[s], kf[s], sacc, 0, 0, 0);

    // prefetch K frags for next tile (hidden under exp + PV)
    {
      size_t kn = (size_t)((kt < T_ / 64 - 1) ? k0 + 64 : k0) * 128;
#pragma unroll
      for (int s = 0; s < 8; ++s) kf[s] = ldfrag(kbase + kn + s * 16);
    }

    // w = exp(exp(s)), diag-adjusted on the diagonal tile only
    int kl = kw + l31;
    if (k0 == q0) {
#pragma unroll
      for (int r = 0; r < 16; ++r) {
        int qrow = qw + (r & 3) + 8 * (r >> 2) + 4 * (lane >> 5);
        if (qrow == kl) sacc[r] *= 0.97790291f;  // 1 - 1/sqrt(2048)
      }
    }
#pragma unroll
    for (int r = 0; r < 16; ++r) {
      int qrow = qw + (r & 3) + 8 * (r >> 2) + 4 * (lane >> 5);
      float w = __expf(__expf(sacc[r]));
      u16 wb = f2bf(w);
      dreg[r] += __uint_as_float((u32)wb << 16);
      wsm[qrow * VSTR + kl] = wb;
    }
    __syncthreads();

    // PV: D[m][q] += V W^T
#pragma unroll
    for (int s2 = 0; s2 < 4; ++s2) {
      bf16x8 wf = ldfrag(&wsm[(qt * 32 + l31) * VSTR + s2 * 16 + lh8]);
      pacc[0] = __builtin_amdgcn_mfma_f32_32x32x16_bf16(vf[s2],     wf, pacc[0], 0, 0, 0);
      pacc[1] = __builtin_amdgcn_mfma_f32_32x32x16_bf16(vf[4 + s2], wf, pacc[1], 0, 0, 0);
    }
    __syncthreads();  // wsm reuse guard
  }

  // denominator reduce
#pragma unroll
  for (int r = 0; r < 16; ++r) {
    float d = dreg[r];
    for (int off = 1; off < 32; off <<= 1) d += __shfl_xor(d, off, 64);
    dreg[r] = d;
  }
  if (l31 == 0) {
#pragma unroll
    for (int r = 0; r < 16; ++r) {
      int qrow = qw + (r & 3) + 8 * (r >> 2) + 4 * (lane >> 5);
      dls[(wv & 1) * 64 + qrow] = dreg[r];
    }
  }
  __syncthreads();

  // P^T bf16 into qsw [q][m]
  {
    int qcol = qt * 32 + l31;
    float rden = 1.f / (dls[qcol] + dls[64 + qcol]);
#pragma unroll
    for (int mi = 0; mi < 2; ++mi) {
      int mbase = (mb + mi) * 32 + 4 * (lane >> 5);
#pragma unroll
      for (int g = 0; g < 4; ++g) {
        float v0 = pacc[mi][4 * g + 0] * rden;
        float v1 = pacc[mi][4 * g + 1] * rden;
        float v2 = pacc[mi][4 * g + 2] * rden;
        float v3 = pacc[mi][4 * g + 3] * rden;
        u32x2 w = {pk2(v0, v1), pk2(v2, v3)};
        *(u32x2*)&qsw[qcol * QSTR + mbase + 8 * g] = w;
      }
    }
  }
  __syncthreads();

  // o-MLP epilogue
  bf16x8 aofr[8];
  {
    const u16* ap = Ao_bf + (wv * 32 + l31) * 128 + lh8;
#pragma unroll
    for (int s = 0; s < 8; ++s) aofr[s] = ldfrag(ap + 16 * s);
  }
#pragma unroll
  for (int qt2 = 0; qt2 < 2; ++qt2) {
    bf16x8 pfr[8];
    const u16* pp = &qsw[(qt2 * 32 + l31) * QSTR + lh8];
#pragma unroll
    for (int s = 0; s < 8; ++s) pfr[s] = ldfrag(pp + 16 * s);
    f32x16 oacc;
#pragma unroll
    for (int r = 0; r < 16; ++r) oacc[r] = 0.f;
#pragma unroll
    for (int s = 0; s < 8; ++s)
      oacc = __builtin_amdgcn_mfma_f32_32x32x16_bf16(aofr[s], pfr[s], oacc, 0, 0, 0);
#pragma unroll
    for (int r = 0; r < 16; ++r) {
      int orow = wv * 32 + (r & 3) + 8 * (r >> 2) + 4 * (lane >> 5);
      float v = oacc[r] + co[orow];
      v = v > 0.f ? v : 0.01f * v;
      out[((size_t)(b * M_ + orow)) * TOUT_ + q0 + qt2 * 32 + l31] = v;
    }
  }

  // rep_ex tail
  if (q0 == 0 && tid < 128) {
    float acc = co[tid];
    const float* mv = meanv + b * 128;
    for (int m = 0; m < 128; ++m) acc = fmaf(Aofp[tid * 128 + m], mv[m], acc);
    acc = acc > 0.f ? acc : 0.01f * acc;
    out[((size_t)(b * M_ + tid)) * TOUT_ + 2048] = acc;
  }
}

// ---------------------------------------------------------------------------
extern "C" void kernel_launch(void* const* d_in, const int* in_sizes, int n_in,
                              void* d_out, int out_size, void* d_ws, size_t ws_size,
                              hipStream_t stream) {
  (void)in_sizes; (void)n_in; (void)out_size; (void)ws_size;
  const float* pattern = (const float*)d_in[0];
  const float* value   = (const float*)d_in[1];
  const float* Wq1 = (const float*)d_in[3];
  const float* bq1 = (const float*)d_in[4];
  const float* Wq2 = (const float*)d_in[5];
  const float* bq2 = (const float*)d_in[6];
  const float* Wk1 = (const float*)d_in[7];
  const float* bk1 = (const float*)d_in[8];
  const float* Wk2 = (const float*)d_in[9];
  const float* bk2 = (const float*)d_in[10];
  const float* Wo1 = (const float*)d_in[11];
  const float* bo1 = (const float*)d_in[12];
  const float* Wo2 = (const float*)d_in[13];
  const float* bo2 = (const float*)d_in[14];

  float* ws     = (float*)d_ws;
  float* A      = ws + A_OFF;
  float* c      = ws + C_OFF;
  float* meanv  = ws + MEAN_OFF;
  u16*   Aqk_bf = (u16*)(ws + AQKBF_OFF);
  u16*   Ao_bf  = (u16*)(ws + AOBF_OFF);
  u16*   qT     = (u16*)(ws + QT_OFF);
  u16*   kT     = (u16*)(ws + KT_OFF);
  u16*   vB     = (u16*)(ws + VB_OFF);
  float* out    = (float*)d_out;

  fuse_weights_all<<<384, 128, 0, stream>>>(
      Wq1, bq1, Wq2, bq2, Wk1, bk1, Wk2, bk2, Wo1, bo1, Wo2, bo2,
      A, c, Aqk_bf, Ao_bf);

  prep_kernel<<<512 + B_ * M_, 256, 0, stream>>>(
      pattern, Aqk_bf, c, qT, kT, value, vB, meanv);

  attn_mfma_kernel<<<dim3(T_ / 64, B_), 256, 0, stream>>>(
      qT, kT, vB, Ao_bf, c + 256, A, meanv, out);
}

// Round 6
// 202.009 us; speedup vs baseline: 1.3152x; 1.3152x over previous
//
#include <hip/hip_runtime.h>
#include <math.h>

#define B_    16
#define M_    128
#define T_    2048
#define H_    512
#define TOUT_ 2049

typedef unsigned short u16;
typedef unsigned int   u32;
typedef __bf16 bf16x8 __attribute__((ext_vector_type(8)));
typedef float  f32x16 __attribute__((ext_vector_type(16)));
typedef u32    u32x4  __attribute__((ext_vector_type(4)));
typedef u32    u32x2  __attribute__((ext_vector_type(2)));

// ws layout (float units):
#define A_OFF     0                       // fp32 Ao only [128][128]
#define C_OFF     16384                   // c[3][128]
#define MEAN_OFF  16896                   // meanv [2048]
#define AQKBF_OFF 19200                   // u16 [256][128] = 16384 fl
#define AOBF_OFF  35584                   // u16 [128][128] = 8192 fl
#define QT_OFF    43776
#define KT_OFF    (43776 + 2097152)
#define VB_OFF    (43776 + 2 * 2097152)

static __device__ __forceinline__ u16 f2bf(float f) {
  u32 u = __float_as_uint(f);
  u = (u + 0x7FFFu + ((u >> 16) & 1u)) >> 16;
  return (u16)u;
}
static __device__ __forceinline__ u32 pk2(float lo, float hi) {
  return (u32)f2bf(lo) | ((u32)f2bf(hi) << 16);
}
static __device__ __forceinline__ bf16x8 ldfrag(const u16* p) {
  return __builtin_bit_cast(bf16x8, *(const u32x4*)p);
}

// ---------------------------------------------------------------------------
__global__ __launch_bounds__(128) void fuse_weights_all(
    const float* __restrict__ W1q, const float* __restrict__ b1q,
    const float* __restrict__ W2q, const float* __restrict__ b2q,
    const float* __restrict__ W1k, const float* __restrict__ b1k,
    const float* __restrict__ W2k, const float* __restrict__ b2k,
    const float* __restrict__ W1o, const float* __restrict__ b1o,
    const float* __restrict__ W2o, const float* __restrict__ b2o,
    float* __restrict__ A, float* __restrict__ c,
    u16* __restrict__ Aqk_bf, u16* __restrict__ Ao_bf) {
  __shared__ float w2row[H_];
  int which = blockIdx.x >> 7;
  int o = blockIdx.x & 127;
  const float* W1 = which == 0 ? W1q : which == 1 ? W1k : W1o;
  const float* b1 = which == 0 ? b1q : which == 1 ? b1k : b1o;
  const float* W2 = which == 0 ? W2q : which == 1 ? W2k : W2o;
  const float* b2 = which == 0 ? b2q : which == 1 ? b2k : b2o;
  int m = threadIdx.x;
  for (int h = m; h < H_; h += 128) w2row[h] = W2[o * H_ + h];
  __syncthreads();
  float acc = 0.f;
#pragma unroll 8
  for (int h = 0; h < H_; ++h) acc = fmaf(w2row[h], W1[h * M_ + m], acc);
  u16 ab = f2bf(acc);
  if (which == 0)      Aqk_bf[o * 128 + m] = ab;
  else if (which == 1) Aqk_bf[(128 + o) * 128 + m] = ab;
  else               { Ao_bf[o * 128 + m] = ab; A[o * M_ + m] = acc; }
  if (m < 64) {
    float cc = 0.f;
    for (int h = m; h < H_; h += 64) cc = fmaf(w2row[h], b1[h], cc);
#pragma unroll
    for (int off = 32; off > 0; off >>= 1) cc += __shfl_down(cc, off, 64);
    if (m == 0) c[which * 128 + o] = cc + b2[o];
  }
}

// ---------------------------------------------------------------------------
// prep: blocks [0,512) = q/k MLP (MFMA, coalesced I/O);
//       blocks [512,2560) = value cast + windowed mean
#define XS 68    // f32 stride of staged pattern [128][68]

__global__ __launch_bounds__(256) void prep_kernel(
    const float* __restrict__ pattern, const u16* __restrict__ Aqk_bf,
    const float* __restrict__ cqk, u16* __restrict__ qT, u16* __restrict__ kT,
    const float* __restrict__ value, u16* __restrict__ vb,
    float* __restrict__ meanv) {
  __shared__ alignas(16) float xsf[128 * XS];  // 34816 B; reused as obuf u16[64][258]
  int bx = blockIdx.x;
  int tid = threadIdx.x;

  if (bx >= 512) {
    int bm = bx - 512;
    float* red = xsf;
    const float* row = value + (size_t)bm * T_;
    int i0 = tid * 8;
    float4 a = *(const float4*)(row + i0);
    float4 bq = *(const float4*)(row + i0 + 4);
    u32x4 o = {pk2(a.x, a.y), pk2(a.z, a.w), pk2(bq.x, bq.y), pk2(bq.z, bq.w)};
    *(u32x4*)&vb[(size_t)bm * T_ + i0] = o;
    float vals[8] = {a.x, a.y, a.z, a.w, bq.x, bq.y, bq.z, bq.w};
    float s = 0.f;
#pragma unroll
    for (int j = 0; j < 8; ++j) {
      int idx = i0 + j;
      if (idx >= 33 && idx < T_ - 1) s += vals[j];
    }
    red[tid] = s;
    __syncthreads();
    for (int st = 128; st > 0; st >>= 1) {
      if (tid < st) red[tid] += red[tid + st];
      __syncthreads();
    }
    if (tid == 0) meanv[bm] = red[0] * (1.f / 2014.f);
    return;
  }

  int b = bx >> 5;
  int t0 = (bx & 31) * 64;
  int lane = tid & 63;
  int wv = tid >> 6;
  int l31 = lane & 31;
  int lh8 = (lane >> 5) * 8;

  bf16x8 afr[2][8];
#pragma unroll
  for (int i = 0; i < 2; ++i) {
    const u16* ap = Aqk_bf + ((2 * wv + i) * 32 + l31) * 128 + lh8;
#pragma unroll
    for (int s = 0; s < 8; ++s) afr[i][s] = ldfrag(ap + 16 * s);
  }

#pragma unroll
  for (int rep = 0; rep < 8; ++rep) {
    int m = rep * 16 + (tid >> 4);
    int tc = (tid & 15) * 4;
    float4 v = *(const float4*)&pattern[(size_t)(b * M_ + m) * T_ + t0 + tc];
    *(float4*)&xsf[m * XS + tc] = v;
  }
  __syncthreads();

  bf16x8 bfr[2][8];
#pragma unroll
  for (int tt = 0; tt < 2; ++tt) {
#pragma unroll
    for (int s = 0; s < 8; ++s) {
      float v0 = xsf[(s * 16 + lh8 + 0) * XS + tt * 32 + l31];
      float v1 = xsf[(s * 16 + lh8 + 1) * XS + tt * 32 + l31];
      float v2 = xsf[(s * 16 + lh8 + 2) * XS + tt * 32 + l31];
      float v3 = xsf[(s * 16 + lh8 + 3) * XS + tt * 32 + l31];
      float v4 = xsf[(s * 16 + lh8 + 4) * XS + tt * 32 + l31];
      float v5 = xsf[(s * 16 + lh8 + 5) * XS + tt * 32 + l31];
      float v6 = xsf[(s * 16 + lh8 + 6) * XS + tt * 32 + l31];
      float v7 = xsf[(s * 16 + lh8 + 7) * XS + tt * 32 + l31];
      u32x4 p = {pk2(v0, v1), pk2(v2, v3), pk2(v4, v5), pk2(v6, v7)};
      bfr[tt][s] = __builtin_bit_cast(bf16x8, p);
    }
  }
  __syncthreads();  // xsf dead -> obuf

  u16* obuf = (u16*)xsf;  // [64 t][258 o]
#pragma unroll
  for (int tt = 0; tt < 2; ++tt) {
#pragma unroll
    for (int i = 0; i < 2; ++i) {
      f32x16 acc;
#pragma unroll
      for (int r = 0; r < 16; ++r) acc[r] = 0.f;
#pragma unroll
      for (int s = 0; s < 8; ++s)
        acc = __builtin_amdgcn_mfma_f32_32x32x16_bf16(afr[i][s], bfr[tt][s], acc, 0, 0, 0);
      int ot = 2 * wv + i;
      int t = tt * 32 + l31;
#pragma unroll
      for (int r = 0; r < 16; ++r) {
        int orow = (r & 3) + 8 * (r >> 2) + 4 * (lane >> 5);
        float v = acc[r] + cqk[ot * 32 + orow];
        v = v > 0.f ? v : 0.01f * v;
        obuf[t * 258 + ot * 32 + orow] = f2bf(v);
      }
    }
  }
  __syncthreads();

  const u32* ob32 = (const u32*)obuf;
#pragma unroll
  for (int g = 0; g < 8; ++g) {
    int G = wv * 8 + g;
    int mat = G >> 4;
    int t = (G & 15) * 4 + (lane >> 4);
    int og2 = lane & 15;
    int wbase = t * 129 + mat * 64 + og2 * 4;
    u32x4 vv = {ob32[wbase], ob32[wbase + 1], ob32[wbase + 2], ob32[wbase + 3]};
    u32* dst = (u32*)((mat ? kT : qT) + ((size_t)(b * T_ + t0 + t)) * 128) + og2 * 4;
    *(u32x4*)dst = vv;
  }
}

// ---------------------------------------------------------------------------
// attn v4: LDS staging (coalesced), vs double-buffered, staging ds_writes
// overlapped with PV => 2 barriers/tile. Fused o-MLP epilogue + rep_ex tail.
#define QSTR 136  // u16: 68 words == 4 mod 32 (conflict-free, measured R2)
#define VSTR 72   // u16: 36 words == 4 mod 32

__global__ __launch_bounds__(256, 2) void attn_mfma_kernel(
    const u16* __restrict__ qT, const u16* __restrict__ kT,
    const u16* __restrict__ vB, const u16* __restrict__ Ao_bf,
    const float* __restrict__ co, const float* __restrict__ Aofp,
    const float* __restrict__ meanv, float* __restrict__ out) {
  __shared__ alignas(16) u16 qsw[64 * QSTR];     // Q stage -> wsm alias -> P^T
  __shared__ alignas(16) u16 ks[64 * QSTR];      // [k][m], single buffer
  __shared__ alignas(16) u16 vs[2][128 * VSTR];  // [m][k], double buffer
  __shared__ float dls[128];

  int b = blockIdx.y;
  int q0 = blockIdx.x * 64;
  int tid = threadIdx.x;
  int lane = tid & 63;
  int wv = tid >> 6;
  int l31 = lane & 31;
  int lh8 = (lane >> 5) * 8;

  // stage Q tile (coalesced)
  {
    const u16* gq = qT + (size_t)(b * T_ + q0) * 128;
#pragma unroll
    for (int it = 0; it < 4; ++it) {
      int r = it * 16 + (tid >> 4);
      int cm = (tid & 15) * 8;
      *(u32x4*)&qsw[r * QSTR + cm] = *(const u32x4*)&gq[r * 128 + cm];
    }
  }

  // staging thread mapping + global bases
  const u16* gkb = kT + (size_t)b * T_ * 128;
  const u16* gvb = vB + (size_t)b * M_ * T_;
  int kr = tid >> 4, kc = (tid & 15) * 8;
  int vr = tid >> 3, vc = (tid & 7) * 8;

  // prologue: load tile 0 into regs
  u32x4 kreg[4], vreg[4];
#pragma unroll
  for (int it = 0; it < 4; ++it) {
    kreg[it] = *(const u32x4*)&gkb[(size_t)(it * 16 + kr) * 128 + kc];
    vreg[it] = *(const u32x4*)&gvb[(size_t)(it * 32 + vr) * T_ + vc];
  }

  __syncthreads();  // Q visible

  int qw = (wv >> 1) * 32;   // S-phase q-half
  int kw = (wv & 1) * 32;    // S-phase k-half
  bf16x8 afrag[8];
  {
    const u16* qrow = &qsw[(qw + l31) * QSTR + lh8];
#pragma unroll
    for (int s = 0; s < 8; ++s) afrag[s] = ldfrag(qrow + s * 16);
  }

  int qt = wv & 1;           // PV q-tile
  int mb = (wv >> 1) * 2;    // PV m-tile base

  // write tile 0 to ks / vs[0] (Q-frag readers synced above; wsm not yet used)
#pragma unroll
  for (int it = 0; it < 4; ++it) {
    *(u32x4*)&ks[(it * 16 + kr) * QSTR + kc] = kreg[it];
    *(u32x4*)&vs[0][(it * 32 + vr) * VSTR + vc] = vreg[it];
  }
  // load tile 1 into regs
#pragma unroll
  for (int it = 0; it < 4; ++it) {
    kreg[it] = *(const u32x4*)&gkb[(size_t)(64 + it * 16 + kr) * 128 + kc];
    vreg[it] = *(const u32x4*)&gvb[(size_t)(it * 32 + vr) * T_ + 64 + vc];
  }

  f32x16 pacc[2];
  float dreg[16];
#pragma unroll
  for (int i = 0; i < 16; ++i) { pacc[0][i] = 0.f; pacc[1][i] = 0.f; dreg[i] = 0.f; }

  for (int kt = 0; kt < T_ / 64; ++kt) {
    int k0 = kt * 64;
    int cur = kt & 1;
    __syncthreads();  // [T] tile-kt staging visible; prev PV readers done

    // S = Q^T K from ks (tile kt)
    f32x16 sacc;
#pragma unroll
    for (int i = 0; i < 16; ++i) sacc[i] = 0.f;
    {
      const u16* krow = &ks[(kw + l31) * QSTR + lh8];
#pragma unroll
      for (int s = 0; s < 8; ++s) {
        bf16x8 bf = ldfrag(krow + s * 16);
        sacc = __builtin_amdgcn_mfma_f32_32x32x16_bf16(afrag[s], bf, sacc, 0, 0, 0);
      }
    }

    // w = exp(exp(s)), diag-adjusted on the diagonal tile
    int kl = kw + l31;
    if (k0 == q0) {
#pragma unroll
      for (int r = 0; r < 16; ++r) {
        int qrow = qw + (r & 3) + 8 * (r >> 2) + 4 * (lane >> 5);
        if (qrow == kl) sacc[r] *= 0.97790291f;  // 1 - 1/sqrt(2048)
      }
    }
#pragma unroll
    for (int r = 0; r < 16; ++r) {
      int qrow = qw + (r & 3) + 8 * (r >> 2) + 4 * (lane >> 5);
      float w = __expf(__expf(sacc[r]));
      u16 wb = f2bf(w);
      dreg[r] += __uint_as_float((u32)wb << 16);
      qsw[qrow * VSTR + kl] = wb;   // wsm aliases Q-stage
    }
    __syncthreads();  // [M] wsm visible; ks/vs[cur] S-readers done

    // overlap with PV: stage tile kt+1 into ks / vs[1-cur]
    if (kt < T_ / 64 - 1) {
#pragma unroll
      for (int it = 0; it < 4; ++it) {
        *(u32x4*)&ks[(it * 16 + kr) * QSTR + kc] = kreg[it];
        *(u32x4*)&vs[1 - cur][(it * 32 + vr) * VSTR + vc] = vreg[it];
      }
      // prefetch tile kt+2
      int kn = (kt + 2 < T_ / 64) ? (kt + 2) * 64 : k0 + 64;
#pragma unroll
      for (int it = 0; it < 4; ++it) {
        kreg[it] = *(const u32x4*)&gkb[(size_t)(kn + it * 16 + kr) * 128 + kc];
        vreg[it] = *(const u32x4*)&gvb[(size_t)(it * 32 + vr) * T_ + kn + vc];
      }
    }

    // PV: D[m][q] += V W^T from wsm + vs[cur]
#pragma unroll
    for (int s2 = 0; s2 < 4; ++s2) {
      bf16x8 wf = ldfrag(&qsw[(qt * 32 + l31) * VSTR + s2 * 16 + lh8]);
      bf16x8 vf0 = ldfrag(&vs[cur][(mb * 32 + l31) * VSTR + s2 * 16 + lh8]);
      bf16x8 vf1 = ldfrag(&vs[cur][((mb + 1) * 32 + l31) * VSTR + s2 * 16 + lh8]);
      pacc[0] = __builtin_amdgcn_mfma_f32_32x32x16_bf16(vf0, wf, pacc[0], 0, 0, 0);
      pacc[1] = __builtin_amdgcn_mfma_f32_32x32x16_bf16(vf1, wf, pacc[1], 0, 0, 0);
    }
  }

  // denominator reduce
#pragma unroll
  for (int r = 0; r < 16; ++r) {
    float d = dreg[r];
    for (int off = 1; off < 32; off <<= 1) d += __shfl_xor(d, off, 64);
    dreg[r] = d;
  }
  if (l31 == 0) {
#pragma unroll
    for (int r = 0; r < 16; ++r) {
      int qrow = qw + (r & 3) + 8 * (r >> 2) + 4 * (lane >> 5);
      dls[(wv & 1) * 64 + qrow] = dreg[r];
    }
  }
  __syncthreads();

  // P^T bf16 into qsw [q][m]
  {
    int qcol = qt * 32 + l31;
    float rden = 1.f / (dls[qcol] + dls[64 + qcol]);
#pragma unroll
    for (int mi = 0; mi < 2; ++mi) {
      int mbase = (mb + mi) * 32 + 4 * (lane >> 5);
#pragma unroll
      for (int g = 0; g < 4; ++g) {
        float v0 = pacc[mi][4 * g + 0] * rden;
        float v1 = pacc[mi][4 * g + 1] * rden;
        float v2 = pacc[mi][4 * g + 2] * rden;
        float v3 = pacc[mi][4 * g + 3] * rden;
        u32x2 w = {pk2(v0, v1), pk2(v2, v3)};
        *(u32x2*)&qsw[qcol * QSTR + mbase + 8 * g] = w;
      }
    }
  }
  __syncthreads();

  // o-MLP epilogue
  bf16x8 aofr[8];
  {
    const u16* ap = Ao_bf + (wv * 32 + l31) * 128 + lh8;
#pragma unroll
    for (int s = 0; s < 8; ++s) aofr[s] = ldfrag(ap + 16 * s);
  }
#pragma unroll
  for (int qt2 = 0; qt2 < 2; ++qt2) {
    bf16x8 pfr[8];
    const u16* pp = &qsw[(qt2 * 32 + l31) * QSTR + lh8];
#pragma unroll
    for (int s = 0; s < 8; ++s) pfr[s] = ldfrag(pp + 16 * s);
    f32x16 oacc;
#pragma unroll
    for (int r = 0; r < 16; ++r) oacc[r] = 0.f;
#pragma unroll
    for (int s = 0; s < 8; ++s)
      oacc = __builtin_amdgcn_mfma_f32_32x32x16_bf16(aofr[s], pfr[s], oacc, 0, 0, 0);
#pragma unroll
    for (int r = 0; r < 16; ++r) {
      int orow = wv * 32 + (r & 3) + 8 * (r >> 2) + 4 * (lane >> 5);
      float v = oacc[r] + co[orow];
      v = v > 0.f ? v : 0.01f * v;
      out[((size_t)(b * M_ + orow)) * TOUT_ + q0 + qt2 * 32 + l31] = v;
    }
  }

  // rep_ex tail
  if (q0 == 0 && tid < 128) {
    float acc = co[tid];
    const float* mv = meanv + b * 128;
    for (int m = 0; m < 128; ++m) acc = fmaf(Aofp[tid * 128 + m], mv[m], acc);
    acc = acc > 0.f ? acc : 0.01f * acc;
    out[((size_t)(b * M_ + tid)) * TOUT_ + 2048] = acc;
  }
}

// ---------------------------------------------------------------------------
extern "C" void kernel_launch(void* const* d_in, const int* in_sizes, int n_in,
                              void* d_out, int out_size, void* d_ws, size_t ws_size,
                              hipStream_t stream) {
  (void)in_sizes; (void)n_in; (void)out_size; (void)ws_size;
  const float* pattern = (const float*)d_in[0];
  const float* value   = (const float*)d_in[1];
  const float* Wq1 = (const float*)d_in[3];
  const float* bq1 = (const float*)d_in[4];
  const float* Wq2 = (const float*)d_in[5];
  const float* bq2 = (const float*)d_in[6];
  const float* Wk1 = (const float*)d_in[7];
  const float* bk1 = (const float*)d_in[8];
  const float* Wk2 = (const float*)d_in[9];
  const float* bk2 = (const float*)d_in[10];
  const float* Wo1 = (const float*)d_in[11];
  const float* bo1 = (const float*)d_in[12];
  const float* Wo2 = (const float*)d_in[13];
  const float* bo2 = (const float*)d_in[14];

  float* ws     = (float*)d_ws;
  float* A      = ws + A_OFF;
  float* c      = ws + C_OFF;
  float* meanv  = ws + MEAN_OFF;
  u16*   Aqk_bf = (u16*)(ws + AQKBF_OFF);
  u16*   Ao_bf  = (u16*)(ws + AOBF_OFF);
  u16*   qT     = (u16*)(ws + QT_OFF);
  u16*   kT     = (u16*)(ws + KT_OFF);
  u16*   vB     = (u16*)(ws + VB_OFF);
  float* out    = (float*)d_out;

  fuse_weights_all<<<384, 128, 0, stream>>>(
      Wq1, bq1, Wq2, bq2, Wk1, bk1, Wk2, bk2, Wo1, bo1, Wo2, bo2,
      A, c, Aqk_bf, Ao_bf);

  prep_kernel<<<512 + B_ * M_, 256, 0, stream>>>(
      pattern, Aqk_bf, c, qT, kT, value, vB, meanv);

  attn_mfma_kernel<<<dim3(T_ / 64, B_), 256, 0, stream>>>(
      qT, kT, vB, Ao_bf, c + 256, A, meanv, out);
}

// Round 8
// 192.761 us; speedup vs baseline: 1.3783x; 1.0480x over previous
//
#include <hip/hip_runtime.h>
#include <hip/hip_bf16.h>
#include <math.h>

#define B_    16
#define M_    128
#define T_    2048
#define H_    512
#define TOUT_ 2049

typedef unsigned short u16;
typedef unsigned int   u32;
typedef __bf16 bf16x8 __attribute__((ext_vector_type(8)));
typedef float  f32x16 __attribute__((ext_vector_type(16)));
typedef u32    u32x4  __attribute__((ext_vector_type(4)));
typedef u32    u32x2  __attribute__((ext_vector_type(2)));

// ws layout (float units):
#define A_OFF     0                       // fp32 Ao only [128][128]
#define C_OFF     16384                   // c[3][128]
#define MEAN_OFF  16896                   // meanv [2048]
#define AQKBF_OFF 19200                   // u16 [256][128] = 16384 fl
#define AOBF_OFF  35584                   // u16 [128][128] = 8192 fl
#define QT_OFF    43776
#define KT_OFF    (43776 + 2097152)
#define VB_OFF    (43776 + 2 * 2097152)

static __device__ __forceinline__ u16 f2bf(float f) {
  u32 u = __float_as_uint(f);
  u = (u + 0x7FFFu + ((u >> 16) & 1u)) >> 16;
  return (u16)u;
}
static __device__ __forceinline__ u32 pk2(float lo, float hi) {
  __hip_bfloat162 h = __float22bfloat162_rn(float2{lo, hi});
  u32 r;
  __builtin_memcpy(&r, &h, 4);   // __hip_bfloat162 not trivially copyable -> no bit_cast
  return r;
}
static __device__ __forceinline__ bf16x8 ldfrag(const u16* p) {
  return __builtin_bit_cast(bf16x8, *(const u32x4*)p);
}

// ---------------------------------------------------------------------------
__global__ __launch_bounds__(128) void fuse_weights_all(
    const float* __restrict__ W1q, const float* __restrict__ b1q,
    const float* __restrict__ W2q, const float* __restrict__ b2q,
    const float* __restrict__ W1k, const float* __restrict__ b1k,
    const float* __restrict__ W2k, const float* __restrict__ b2k,
    const float* __restrict__ W1o, const float* __restrict__ b1o,
    const float* __restrict__ W2o, const float* __restrict__ b2o,
    float* __restrict__ A, float* __restrict__ c,
    u16* __restrict__ Aqk_bf, u16* __restrict__ Ao_bf) {
  __shared__ float w2row[H_];
  int which = blockIdx.x >> 7;
  int o = blockIdx.x & 127;
  const float* W1 = which == 0 ? W1q : which == 1 ? W1k : W1o;
  const float* b1 = which == 0 ? b1q : which == 1 ? b1k : b1o;
  const float* W2 = which == 0 ? W2q : which == 1 ? W2k : W2o;
  const float* b2 = which == 0 ? b2q : which == 1 ? b2k : b2o;
  int m = threadIdx.x;
  for (int h = m; h < H_; h += 128) w2row[h] = W2[o * H_ + h];
  __syncthreads();
  float acc = 0.f;
#pragma unroll 8
  for (int h = 0; h < H_; ++h) acc = fmaf(w2row[h], W1[h * M_ + m], acc);
  u16 ab = f2bf(acc);
  if (which == 0)      Aqk_bf[o * 128 + m] = ab;
  else if (which == 1) Aqk_bf[(128 + o) * 128 + m] = ab;
  else               { Ao_bf[o * 128 + m] = ab; A[o * M_ + m] = acc; }
  if (m < 64) {
    float cc = 0.f;
    for (int h = m; h < H_; h += 64) cc = fmaf(w2row[h], b1[h], cc);
#pragma unroll
    for (int off = 32; off > 0; off >>= 1) cc += __shfl_down(cc, off, 64);
    if (m == 0) c[which * 128 + o] = cc + b2[o];
  }
}

// ---------------------------------------------------------------------------
// prep: blocks [0,512) = q/k MLP (MFMA, coalesced I/O);
//       blocks [512,2560) = value cast + windowed mean
#define XS 68    // f32 stride of staged pattern [128][68]

__global__ __launch_bounds__(256) void prep_kernel(
    const float* __restrict__ pattern, const u16* __restrict__ Aqk_bf,
    const float* __restrict__ cqk, u16* __restrict__ qT, u16* __restrict__ kT,
    const float* __restrict__ value, u16* __restrict__ vb,
    float* __restrict__ meanv) {
  __shared__ alignas(16) float xsf[128 * XS];  // 34816 B; reused as obuf u16[64][258]
  int bx = blockIdx.x;
  int tid = threadIdx.x;

  if (bx >= 512) {
    int bm = bx - 512;
    float* red = xsf;
    const float* row = value + (size_t)bm * T_;
    int i0 = tid * 8;
    float4 a = *(const float4*)(row + i0);
    float4 bq = *(const float4*)(row + i0 + 4);
    u32x4 o = {pk2(a.x, a.y), pk2(a.z, a.w), pk2(bq.x, bq.y), pk2(bq.z, bq.w)};
    *(u32x4*)&vb[(size_t)bm * T_ + i0] = o;
    float vals[8] = {a.x, a.y, a.z, a.w, bq.x, bq.y, bq.z, bq.w};
    float s = 0.f;
#pragma unroll
    for (int j = 0; j < 8; ++j) {
      int idx = i0 + j;
      if (idx >= 33 && idx < T_ - 1) s += vals[j];
    }
    red[tid] = s;
    __syncthreads();
    for (int st = 128; st > 0; st >>= 1) {
      if (tid < st) red[tid] += red[tid + st];
      __syncthreads();
    }
    if (tid == 0) meanv[bm] = red[0] * (1.f / 2014.f);
    return;
  }

  int b = bx >> 5;
  int t0 = (bx & 31) * 64;
  int lane = tid & 63;
  int wv = tid >> 6;
  int l31 = lane & 31;
  int lh8 = (lane >> 5) * 8;

  bf16x8 afr[2][8];
#pragma unroll
  for (int i = 0; i < 2; ++i) {
    const u16* ap = Aqk_bf + ((2 * wv + i) * 32 + l31) * 128 + lh8;
#pragma unroll
    for (int s = 0; s < 8; ++s) afr[i][s] = ldfrag(ap + 16 * s);
  }

#pragma unroll
  for (int rep = 0; rep < 8; ++rep) {
    int m = rep * 16 + (tid >> 4);
    int tc = (tid & 15) * 4;
    float4 v = *(const float4*)&pattern[(size_t)(b * M_ + m) * T_ + t0 + tc];
    *(float4*)&xsf[m * XS + tc] = v;
  }
  __syncthreads();

  bf16x8 bfr[2][8];
#pragma unroll
  for (int tt = 0; tt < 2; ++tt) {
#pragma unroll
    for (int s = 0; s < 8; ++s) {
      float v0 = xsf[(s * 16 + lh8 + 0) * XS + tt * 32 + l31];
      float v1 = xsf[(s * 16 + lh8 + 1) * XS + tt * 32 + l31];
      float v2 = xsf[(s * 16 + lh8 + 2) * XS + tt * 32 + l31];
      float v3 = xsf[(s * 16 + lh8 + 3) * XS + tt * 32 + l31];
      float v4 = xsf[(s * 16 + lh8 + 4) * XS + tt * 32 + l31];
      float v5 = xsf[(s * 16 + lh8 + 5) * XS + tt * 32 + l31];
      float v6 = xsf[(s * 16 + lh8 + 6) * XS + tt * 32 + l31];
      float v7 = xsf[(s * 16 + lh8 + 7) * XS + tt * 32 + l31];
      u32x4 p = {pk2(v0, v1), pk2(v2, v3), pk2(v4, v5), pk2(v6, v7)};
      bfr[tt][s] = __builtin_bit_cast(bf16x8, p);
    }
  }
  __syncthreads();  // xsf dead -> obuf

  u16* obuf = (u16*)xsf;  // [64 t][258 o]
#pragma unroll
  for (int tt = 0; tt < 2; ++tt) {
#pragma unroll
    for (int i = 0; i < 2; ++i) {
      f32x16 acc;
#pragma unroll
      for (int r = 0; r < 16; ++r) acc[r] = 0.f;
#pragma unroll
      for (int s = 0; s < 8; ++s)
        acc = __builtin_amdgcn_mfma_f32_32x32x16_bf16(afr[i][s], bfr[tt][s], acc, 0, 0, 0);
      int ot = 2 * wv + i;
      int t = tt * 32 + l31;
#pragma unroll
      for (int r = 0; r < 16; ++r) {
        int orow = (r & 3) + 8 * (r >> 2) + 4 * (lane >> 5);
        float v = acc[r] + cqk[ot * 32 + orow];
        v = v > 0.f ? v : 0.01f * v;
        obuf[t * 258 + ot * 32 + orow] = f2bf(v);
      }
    }
  }
  __syncthreads();

  const u32* ob32 = (const u32*)obuf;
#pragma unroll
  for (int g = 0; g < 8; ++g) {
    int G = wv * 8 + g;
    int mat = G >> 4;
    int t = (G & 15) * 4 + (lane >> 4);
    int og2 = lane & 15;
    int wbase = t * 129 + mat * 64 + og2 * 4;
    u32x4 vv = {ob32[wbase], ob32[wbase + 1], ob32[wbase + 2], ob32[wbase + 3]};
    u32* dst = (u32*)((mat ? kT : qT) + ((size_t)(b * T_ + t0 + t)) * 128) + og2 * 4;
    *(u32x4*)dst = vv;
  }
}

// ---------------------------------------------------------------------------
// attn v5: TQ=128 per 512-thread block (1 block/CU), TK=64, 2 barriers/tile,
// vs double-buffered, staging overlapped with PV, dynamic LDS 90112 B.
// Fused o-MLP epilogue + rep_ex tail.
#define QSTR 136  // u16: 68 words == 4 mod 32 (conflict-free, measured R2)
#define VSTR 72   // u16: 36 words == 4 mod 32
#define NKT  (T_ / 64)

__global__ __launch_bounds__(512, 2) void attn_mfma_kernel(
    const u16* __restrict__ qT, const u16* __restrict__ kT,
    const u16* __restrict__ vB, const u16* __restrict__ Ao_bf,
    const float* __restrict__ co, const float* __restrict__ Aofp,
    const float* __restrict__ meanv, float* __restrict__ out) {
  extern __shared__ u16 smem[];
  u16* qsw = smem;                        // [128][QSTR]: Q -> wsm[128][VSTR] -> P^T
  u16* ks  = smem + 128 * QSTR;           // [64][QSTR]
  u16* vs0 = ks + 64 * QSTR;              // [128][VSTR] x2 (dbuf)
  u16* vs1 = vs0 + 128 * VSTR;
  float* dls = (float*)(vs1 + 128 * VSTR);  // [2][128]

  int b = blockIdx.y;
  int q0 = blockIdx.x * 128;
  int tid = threadIdx.x;
  int lane = tid & 63;
  int wv = tid >> 6;                 // 0..7
  int l31 = lane & 31;
  int lh8 = (lane >> 5) * 8;

  // stage Q tile [128 q][128 m] (coalesced)
  {
    const u16* gq = qT + (size_t)(b * T_ + q0) * 128;
#pragma unroll
    for (int it = 0; it < 4; ++it) {
      int r = it * 32 + (tid >> 4);
      int cm = (tid & 15) * 8;
      *(u32x4*)&qsw[r * QSTR + cm] = *(const u32x4*)&gq[r * 128 + cm];
    }
  }

  // staging mapping + global bases
  const u16* gkb = kT + (size_t)b * T_ * 128;
  const u16* gvb = vB + (size_t)b * M_ * T_;
  int kr = tid >> 4, kc = (tid & 15) * 8;   // K: rows it*32+kr, 2 its
  int vr = tid >> 3, vc = (tid & 7) * 8;    // V: rows it*64+vr, 2 its

  u32x4 kreg[2], vreg[2];
#pragma unroll
  for (int it = 0; it < 2; ++it) {
    kreg[it] = *(const u32x4*)&gkb[(size_t)(it * 32 + kr) * 128 + kc];
    vreg[it] = *(const u32x4*)&gvb[(size_t)(it * 64 + vr) * T_ + vc];
  }

  __syncthreads();  // Q visible

  int qw = (wv & 3) * 32;    // S-phase q-tile
  int kw = (wv >> 2) * 32;   // S-phase k-half
  bf16x8 afrag[8];
  {
    const u16* qrow = &qsw[(qw + l31) * QSTR + lh8];
#pragma unroll
    for (int s = 0; s < 8; ++s) afrag[s] = ldfrag(qrow + s * 16);
  }

  int qt = wv & 3;           // PV q-tile
  int mb = (wv >> 2) * 2;    // PV m-tile base

  // write tile 0 (doesn't touch qsw; Q-frag loads ordered by program order)
#pragma unroll
  for (int it = 0; it < 2; ++it) {
    *(u32x4*)&ks[(it * 32 + kr) * QSTR + kc] = kreg[it];
    *(u32x4*)&vs0[(it * 64 + vr) * VSTR + vc] = vreg[it];
  }
  // load tile 1
#pragma unroll
  for (int it = 0; it < 2; ++it) {
    kreg[it] = *(const u32x4*)&gkb[(size_t)(64 + it * 32 + kr) * 128 + kc];
    vreg[it] = *(const u32x4*)&gvb[(size_t)(it * 64 + vr) * T_ + 64 + vc];
  }

  f32x16 pacc[2];
  float dreg[16];
#pragma unroll
  for (int i = 0; i < 16; ++i) { pacc[0][i] = 0.f; pacc[1][i] = 0.f; dreg[i] = 0.f; }

  for (int kt = 0; kt < NKT; ++kt) {
    int k0 = kt * 64;
    u16* vcur = (kt & 1) ? vs1 : vs0;
    u16* vnxt = (kt & 1) ? vs0 : vs1;
    __syncthreads();  // [T] staging of tile kt visible

    // S = Q^T K
    f32x16 sacc;
#pragma unroll
    for (int i = 0; i < 16; ++i) sacc[i] = 0.f;
    {
      const u16* krow = &ks[(kw + l31) * QSTR + lh8];
#pragma unroll
      for (int s = 0; s < 8; ++s) {
        bf16x8 bf = ldfrag(krow + s * 16);
        sacc = __builtin_amdgcn_mfma_f32_32x32x16_bf16(afrag[s], bf, sacc, 0, 0, 0);
      }
    }

    // w = exp(exp(s)), diag-adjust, pairwise bf16 pack, wsm scatter + den
    int kl = kw + l31;
    if (q0 + qw == k0 + kw) {
#pragma unroll
      for (int r = 0; r < 16; ++r) {
        int qrow = qw + (r & 3) + 8 * (r >> 2) + 4 * (lane >> 5);
        if (qrow == kl + (k0 - q0)) sacc[r] *= 0.97790291f;  // 1 - 1/sqrt(2048)
      }
    }
#pragma unroll
    for (int r = 0; r < 16; r += 2) {
      int qrow = qw + (r & 3) + 8 * (r >> 2) + 4 * (lane >> 5);
      float w0 = __expf(__expf(sacc[r]));
      float w1 = __expf(__expf(sacc[r + 1]));
      u32 p = pk2(w0, w1);
      dreg[r]     += __uint_as_float(p << 16);
      dreg[r + 1] += __uint_as_float(p & 0xffff0000u);
      qsw[qrow * VSTR + kl]       = (u16)p;        // wsm aliases Q-stage
      qsw[(qrow + 1) * VSTR + kl] = (u16)(p >> 16);
    }
    __syncthreads();  // [M] wsm visible; S-reads of ks done

    // overlap with PV: stage tile kt+1, prefetch tile kt+2
    if (kt < NKT - 1) {
#pragma unroll
      for (int it = 0; it < 2; ++it) {
        *(u32x4*)&ks[(it * 32 + kr) * QSTR + kc] = kreg[it];
        *(u32x4*)&vnxt[(it * 64 + vr) * VSTR + vc] = vreg[it];
      }
      int kn = (kt + 2 < NKT) ? (kt + 2) * 64 : (NKT - 1) * 64;
#pragma unroll
      for (int it = 0; it < 2; ++it) {
        kreg[it] = *(const u32x4*)&gkb[(size_t)(kn + it * 32 + kr) * 128 + kc];
        vreg[it] = *(const u32x4*)&gvb[(size_t)(it * 64 + vr) * T_ + kn + vc];
      }
    }

    // PV: D[m][q] += V W^T
#pragma unroll
    for (int s2 = 0; s2 < 4; ++s2) {
      bf16x8 wf = ldfrag(&qsw[(qt * 32 + l31) * VSTR + s2 * 16 + lh8]);
      bf16x8 vf0 = ldfrag(&vcur[(mb * 32 + l31) * VSTR + s2 * 16 + lh8]);
      bf16x8 vf1 = ldfrag(&vcur[((mb + 1) * 32 + l31) * VSTR + s2 * 16 + lh8]);
      pacc[0] = __builtin_amdgcn_mfma_f32_32x32x16_bf16(vf0, wf, pacc[0], 0, 0, 0);
      pacc[1] = __builtin_amdgcn_mfma_f32_32x32x16_bf16(vf1, wf, pacc[1], 0, 0, 0);
    }
  }

  // denominator reduce (sum over 32 k-lanes of each half-wave)
#pragma unroll
  for (int r = 0; r < 16; ++r) {
    float d = dreg[r];
    for (int off = 1; off < 32; off <<= 1) d += __shfl_xor(d, off, 64);
    dreg[r] = d;
  }
  if (l31 == 0) {
#pragma unroll
    for (int r = 0; r < 16; ++r) {
      int qrow = qw + (r & 3) + 8 * (r >> 2) + 4 * (lane >> 5);
      dls[(wv >> 2) * 128 + qrow] = dreg[r];
    }
  }
  __syncthreads();  // dls visible; last PV's wsm reads fenced

  // P^T bf16 into qsw [q][m]
  {
    int qcol = qt * 32 + l31;
    float rden = 1.f / (dls[qcol] + dls[128 + qcol]);
#pragma unroll
    for (int mi = 0; mi < 2; ++mi) {
      int mbase = (mb + mi) * 32 + 4 * (lane >> 5);
#pragma unroll
      for (int g = 0; g < 4; ++g) {
        float v0 = pacc[mi][4 * g + 0] * rden;
        float v1 = pacc[mi][4 * g + 1] * rden;
        float v2 = pacc[mi][4 * g + 2] * rden;
        float v3 = pacc[mi][4 * g + 3] * rden;
        u32x2 w = {pk2(v0, v1), pk2(v2, v3)};
        *(u32x2*)&qsw[qcol * QSTR + mbase + 8 * g] = w;
      }
    }
  }
  __syncthreads();

  // o-MLP epilogue: wave wv -> o-tile (wv&3), q-tiles {2*(wv>>2), +1}
  bf16x8 aofr[8];
  {
    const u16* ap = Ao_bf + ((wv & 3) * 32 + l31) * 128 + lh8;
#pragma unroll
    for (int s = 0; s < 8; ++s) aofr[s] = ldfrag(ap + 16 * s);
  }
#pragma unroll
  for (int j = 0; j < 2; ++j) {
    int qt2 = (wv >> 2) * 2 + j;
    bf16x8 pfr[8];
    const u16* pp = &qsw[(qt2 * 32 + l31) * QSTR + lh8];
#pragma unroll
    for (int s = 0; s < 8; ++s) pfr[s] = ldfrag(pp + 16 * s);
    f32x16 oacc;
#pragma unroll
    for (int r = 0; r < 16; ++r) oacc[r] = 0.f;
#pragma unroll
    for (int s = 0; s < 8; ++s)
      oacc = __builtin_amdgcn_mfma_f32_32x32x16_bf16(aofr[s], pfr[s], oacc, 0, 0, 0);
#pragma unroll
    for (int r = 0; r < 16; ++r) {
      int orow = (wv & 3) * 32 + (r & 3) + 8 * (r >> 2) + 4 * (lane >> 5);
      float v = oacc[r] + co[orow];
      v = v > 0.f ? v : 0.01f * v;
      out[((size_t)(b * M_ + orow)) * TOUT_ + q0 + qt2 * 32 + l31] = v;
    }
  }

  // rep_ex tail
  if (blockIdx.x == 0 && tid < 128) {
    float acc = co[tid];
    const float* mv = meanv + b * 128;
    for (int m = 0; m < 128; ++m) acc = fmaf(Aofp[tid * 128 + m], mv[m], acc);
    acc = acc > 0.f ? acc : 0.01f * acc;
    out[((size_t)(b * M_ + tid)) * TOUT_ + 2048] = acc;
  }
}

// ---------------------------------------------------------------------------
extern "C" void kernel_launch(void* const* d_in, const int* in_sizes, int n_in,
                              void* d_out, int out_size, void* d_ws, size_t ws_size,
                              hipStream_t stream) {
  (void)in_sizes; (void)n_in; (void)out_size; (void)ws_size;
  const float* pattern = (const float*)d_in[0];
  const float* value   = (const float*)d_in[1];
  const float* Wq1 = (const float*)d_in[3];
  const float* bq1 = (const float*)d_in[4];
  const float* Wq2 = (const float*)d_in[5];
  const float* bq2 = (const float*)d_in[6];
  const float* Wk1 = (const float*)d_in[7];
  const float* bk1 = (const float*)d_in[8];
  const float* Wk2 = (const float*)d_in[9];
  const float* bk2 = (const float*)d_in[10];
  const float* Wo1 = (const float*)d_in[11];
  const float* bo1 = (const float*)d_in[12];
  const float* Wo2 = (const float*)d_in[13];
  const float* bo2 = (const float*)d_in[14];

  float* ws     = (float*)d_ws;
  float* A      = ws + A_OFF;
  float* c      = ws + C_OFF;
  float* meanv  = ws + MEAN_OFF;
  u16*   Aqk_bf = (u16*)(ws + AQKBF_OFF);
  u16*   Ao_bf  = (u16*)(ws + AOBF_OFF);
  u16*   qT     = (u16*)(ws + QT_OFF);
  u16*   kT     = (u16*)(ws + KT_OFF);
  u16*   vB     = (u16*)(ws + VB_OFF);
  float* out    = (float*)d_out;

  fuse_weights_all<<<384, 128, 0, stream>>>(
      Wq1, bq1, Wq2, bq2, Wk1, bk1, Wk2, bk2, Wo1, bo1, Wo2, bo2,
      A, c, Aqk_bf, Ao_bf);

  prep_kernel<<<512 + B_ * M_, 256, 0, stream>>>(
      pattern, Aqk_bf, c, qT, kT, value, vB, meanv);

  size_t lds_bytes = (128 * QSTR + 64 * QSTR + 2 * 128 * VSTR) * sizeof(u16)
                   + 256 * sizeof(float);  // 90112
  attn_mfma_kernel<<<dim3(T_ / 128, B_), 512, lds_bytes, stream>>>(
      qT, kT, vB, Ao_bf, c + 256, A, meanv, out);
}

// Round 9
// 190.631 us; speedup vs baseline: 1.3937x; 1.0112x over previous
//
#include <hip/hip_runtime.h>
#include <hip/hip_bf16.h>
#include <math.h>

#define B_    16
#define M_    128
#define T_    2048
#define H_    512
#define TOUT_ 2049

typedef unsigned short u16;
typedef unsigned int   u32;
typedef __bf16 bf16x8 __attribute__((ext_vector_type(8)));
typedef float  f32x16 __attribute__((ext_vector_type(16)));
typedef float  f32x4  __attribute__((ext_vector_type(4)));
typedef u32    u32x4  __attribute__((ext_vector_type(4)));
typedef u32    u32x2  __attribute__((ext_vector_type(2)));

// ws layout (float units):
#define A_OFF     0                       // fp32 Ao only [128][128]
#define C_OFF     16384                   // c[3][128]
#define MEAN_OFF  16896                   // meanv [2048]
#define AQKBF_OFF 19200                   // u16 [256][128] = 16384 fl
#define AOBF_OFF  35584                   // u16 [128][128] = 8192 fl
#define QT_OFF    43776
#define KT_OFF    (43776 + 2097152)
#define VB_OFF    (43776 + 2 * 2097152)

static __device__ __forceinline__ u16 f2bf(float f) {
  u32 u = __float_as_uint(f);
  u = (u + 0x7FFFu + ((u >> 16) & 1u)) >> 16;
  return (u16)u;
}
static __device__ __forceinline__ u32 pk2(float lo, float hi) {
  __hip_bfloat162 h = __float22bfloat162_rn(float2{lo, hi});
  u32 r;
  __builtin_memcpy(&r, &h, 4);
  return r;
}
static __device__ __forceinline__ bf16x8 ldfrag(const u16* p) {
  return __builtin_bit_cast(bf16x8, *(const u32x4*)p);
}

// ---------------------------------------------------------------------------
__global__ __launch_bounds__(128) void fuse_weights_all(
    const float* __restrict__ W1q, const float* __restrict__ b1q,
    const float* __restrict__ W2q, const float* __restrict__ b2q,
    const float* __restrict__ W1k, const float* __restrict__ b1k,
    const float* __restrict__ W2k, const float* __restrict__ b2k,
    const float* __restrict__ W1o, const float* __restrict__ b1o,
    const float* __restrict__ W2o, const float* __restrict__ b2o,
    float* __restrict__ A, float* __restrict__ c,
    u16* __restrict__ Aqk_bf, u16* __restrict__ Ao_bf) {
  __shared__ float w2row[H_];
  int which = blockIdx.x >> 7;
  int o = blockIdx.x & 127;
  const float* W1 = which == 0 ? W1q : which == 1 ? W1k : W1o;
  const float* b1 = which == 0 ? b1q : which == 1 ? b1k : b1o;
  const float* W2 = which == 0 ? W2q : which == 1 ? W2k : W2o;
  const float* b2 = which == 0 ? b2q : which == 1 ? b2k : b2o;
  int m = threadIdx.x;
  for (int h = m; h < H_; h += 128) w2row[h] = W2[o * H_ + h];
  __syncthreads();
  float acc = 0.f;
#pragma unroll 8
  for (int h = 0; h < H_; ++h) acc = fmaf(w2row[h], W1[h * M_ + m], acc);
  u16 ab = f2bf(acc);
  if (which == 0)      Aqk_bf[o * 128 + m] = ab;
  else if (which == 1) Aqk_bf[(128 + o) * 128 + m] = ab;
  else               { Ao_bf[o * 128 + m] = ab; A[o * M_ + m] = acc; }
  if (m < 64) {
    float cc = 0.f;
    for (int h = m; h < H_; h += 64) cc = fmaf(w2row[h], b1[h], cc);
#pragma unroll
    for (int off = 32; off > 0; off >>= 1) cc += __shfl_down(cc, off, 64);
    if (m == 0) c[which * 128 + o] = cc + b2[o];
  }
}

// ---------------------------------------------------------------------------
// prep: blocks [0,512) = q/k MLP (MFMA, coalesced I/O);
//       blocks [512,2560) = value cast + windowed mean
#define XS 68

__global__ __launch_bounds__(256) void prep_kernel(
    const float* __restrict__ pattern, const u16* __restrict__ Aqk_bf,
    const float* __restrict__ cqk, u16* __restrict__ qT, u16* __restrict__ kT,
    const float* __restrict__ value, u16* __restrict__ vb,
    float* __restrict__ meanv) {
  __shared__ alignas(16) float xsf[128 * XS];
  int bx = blockIdx.x;
  int tid = threadIdx.x;

  if (bx >= 512) {
    int bm = bx - 512;
    float* red = xsf;
    const float* row = value + (size_t)bm * T_;
    int i0 = tid * 8;
    float4 a = *(const float4*)(row + i0);
    float4 bq = *(const float4*)(row + i0 + 4);
    u32x4 o = {pk2(a.x, a.y), pk2(a.z, a.w), pk2(bq.x, bq.y), pk2(bq.z, bq.w)};
    *(u32x4*)&vb[(size_t)bm * T_ + i0] = o;
    float vals[8] = {a.x, a.y, a.z, a.w, bq.x, bq.y, bq.z, bq.w};
    float s = 0.f;
#pragma unroll
    for (int j = 0; j < 8; ++j) {
      int idx = i0 + j;
      if (idx >= 33 && idx < T_ - 1) s += vals[j];
    }
    red[tid] = s;
    __syncthreads();
    for (int st = 128; st > 0; st >>= 1) {
      if (tid < st) red[tid] += red[tid + st];
      __syncthreads();
    }
    if (tid == 0) meanv[bm] = red[0] * (1.f / 2014.f);
    return;
  }

  int b = bx >> 5;
  int t0 = (bx & 31) * 64;
  int lane = tid & 63;
  int wv = tid >> 6;
  int l31 = lane & 31;
  int lh8 = (lane >> 5) * 8;

  bf16x8 afr[2][8];
#pragma unroll
  for (int i = 0; i < 2; ++i) {
    const u16* ap = Aqk_bf + ((2 * wv + i) * 32 + l31) * 128 + lh8;
#pragma unroll
    for (int s = 0; s < 8; ++s) afr[i][s] = ldfrag(ap + 16 * s);
  }

#pragma unroll
  for (int rep = 0; rep < 8; ++rep) {
    int m = rep * 16 + (tid >> 4);
    int tc = (tid & 15) * 4;
    float4 v = *(const float4*)&pattern[(size_t)(b * M_ + m) * T_ + t0 + tc];
    *(float4*)&xsf[m * XS + tc] = v;
  }
  __syncthreads();

  bf16x8 bfr[2][8];
#pragma unroll
  for (int tt = 0; tt < 2; ++tt) {
#pragma unroll
    for (int s = 0; s < 8; ++s) {
      float v0 = xsf[(s * 16 + lh8 + 0) * XS + tt * 32 + l31];
      float v1 = xsf[(s * 16 + lh8 + 1) * XS + tt * 32 + l31];
      float v2 = xsf[(s * 16 + lh8 + 2) * XS + tt * 32 + l31];
      float v3 = xsf[(s * 16 + lh8 + 3) * XS + tt * 32 + l31];
      float v4 = xsf[(s * 16 + lh8 + 4) * XS + tt * 32 + l31];
      float v5 = xsf[(s * 16 + lh8 + 5) * XS + tt * 32 + l31];
      float v6 = xsf[(s * 16 + lh8 + 6) * XS + tt * 32 + l31];
      float v7 = xsf[(s * 16 + lh8 + 7) * XS + tt * 32 + l31];
      u32x4 p = {pk2(v0, v1), pk2(v2, v3), pk2(v4, v5), pk2(v6, v7)};
      bfr[tt][s] = __builtin_bit_cast(bf16x8, p);
    }
  }
  __syncthreads();  // xsf dead -> obuf

  u16* obuf = (u16*)xsf;  // [64 t][258 o]
#pragma unroll
  for (int tt = 0; tt < 2; ++tt) {
#pragma unroll
    for (int i = 0; i < 2; ++i) {
      f32x16 acc;
#pragma unroll
      for (int r = 0; r < 16; ++r) acc[r] = 0.f;
#pragma unroll
      for (int s = 0; s < 8; ++s)
        acc = __builtin_amdgcn_mfma_f32_32x32x16_bf16(afr[i][s], bfr[tt][s], acc, 0, 0, 0);
      int ot = 2 * wv + i;
      int t = tt * 32 + l31;
#pragma unroll
      for (int r = 0; r < 16; ++r) {
        int orow = (r & 3) + 8 * (r >> 2) + 4 * (lane >> 5);
        float v = acc[r] + cqk[ot * 32 + orow];
        v = v > 0.f ? v : 0.01f * v;
        obuf[t * 258 + ot * 32 + orow] = f2bf(v);
      }
    }
  }
  __syncthreads();

  const u32* ob32 = (const u32*)obuf;
#pragma unroll
  for (int g = 0; g < 8; ++g) {
    int G = wv * 8 + g;
    int mat = G >> 4;
    int t = (G & 15) * 4 + (lane >> 4);
    int og2 = lane & 15;
    int wbase = t * 129 + mat * 64 + og2 * 4;
    u32x4 vv = {ob32[wbase], ob32[wbase + 1], ob32[wbase + 2], ob32[wbase + 3]};
    u32* dst = (u32*)((mat ? kT : qT) + ((size_t)(b * T_ + t0 + t)) * 128) + og2 * 4;
    *(u32x4*)dst = vv;
  }
}

// ---------------------------------------------------------------------------
// attn v6: S computed TRANSPOSED (S'[k][q] = mfma(K,Q)), exp in-register,
// B-frag for PV assembled via shfl_xor(32) half-wave exchange -> no wsm LDS
// round-trip, no intra-tile cross-wave dependency -> 1 barrier/tile.
// Each wave: PV partials over its 32-k half for all 128 m; wave pairs combine
// once in the epilogue. K/V double-buffered. TQ=128, 512 thr, 1 block/CU.
#define QSTR 136  // u16: 68 words == 4 mod 32 (conflict-free)
#define VSTR 72   // u16: 36 words == 4 mod 32
#define NKT  (T_ / 64)

__global__ __launch_bounds__(512, 2) void attn_mfma_kernel(
    const u16* __restrict__ qT, const u16* __restrict__ kT,
    const u16* __restrict__ vB, const u16* __restrict__ Ao_bf,
    const float* __restrict__ co, const float* __restrict__ Aofp,
    const float* __restrict__ meanv, float* __restrict__ out) {
  extern __shared__ u16 smem[];
  u16* qsw = smem;                        // [128][QSTR]: Q -> P^T
  u16* ks0 = smem + 128 * QSTR;           // [64][QSTR] x2 (dbuf)
  u16* ks1 = ks0 + 64 * QSTR;
  u16* vs0 = ks1 + 64 * QSTR;             // [128][VSTR] x2 (dbuf)
  u16* vs1 = vs0 + 128 * VSTR;
  float* dls  = (float*)(vs1 + 128 * VSTR);  // [128]
  float* pbuf = (float*)ks0;              // 64 KB epilogue alias (ks+vs dead)

  int b = blockIdx.y;
  int q0 = blockIdx.x * 128;
  int tid = threadIdx.x;
  int lane = tid & 63;
  int wv = tid >> 6;                 // 0..7
  int l31 = lane & 31;
  int h = lane >> 5;
  int lh8 = h * 8;
  int qt = wv & 3;                   // q-tile (32 q's)
  int kh = wv >> 2;                  // k-half of each 64-k tile

  // stage Q tile [128 q][128 m] (coalesced)
  {
    const u16* gq = qT + (size_t)(b * T_ + q0) * 128;
#pragma unroll
    for (int it = 0; it < 4; ++it) {
      int r = it * 32 + (tid >> 4);
      int cm = (tid & 15) * 8;
      *(u32x4*)&qsw[r * QSTR + cm] = *(const u32x4*)&gq[r * 128 + cm];
    }
  }

  const u16* gkb = kT + (size_t)b * T_ * 128;
  const u16* gvb = vB + (size_t)b * M_ * T_;
  int kr = tid >> 4, kc = (tid & 15) * 8;
  int vr = tid >> 3, vc = (tid & 7) * 8;

  u32x4 kreg[2], vreg[2];
#pragma unroll
  for (int it = 0; it < 2; ++it) {
    kreg[it] = *(const u32x4*)&gkb[(size_t)(it * 32 + kr) * 128 + kc];
    vreg[it] = *(const u32x4*)&gvb[(size_t)(it * 64 + vr) * T_ + vc];
  }

  __syncthreads();  // Q visible

  // persistent Q B-frags (this wave's 32 q's)
  bf16x8 qfrag[8];
  {
    const u16* qrow = &qsw[(qt * 32 + l31) * QSTR + lh8];
#pragma unroll
    for (int s = 0; s < 8; ++s) qfrag[s] = ldfrag(qrow + s * 16);
  }

  // write tile 0, load tile 1
#pragma unroll
  for (int it = 0; it < 2; ++it) {
    *(u32x4*)&ks0[(it * 32 + kr) * QSTR + kc] = kreg[it];
    *(u32x4*)&vs0[(it * 64 + vr) * VSTR + vc] = vreg[it];
  }
#pragma unroll
  for (int it = 0; it < 2; ++it) {
    kreg[it] = *(const u32x4*)&gkb[(size_t)(64 + it * 32 + kr) * 128 + kc];
    vreg[it] = *(const u32x4*)&gvb[(size_t)(it * 64 + vr) * T_ + 64 + vc];
  }

  f32x16 pacc[4];
  float den = 0.f;
#pragma unroll
  for (int i = 0; i < 16; ++i) {
    pacc[0][i] = 0.f; pacc[1][i] = 0.f; pacc[2][i] = 0.f; pacc[3][i] = 0.f;
  }

  for (int kt = 0; kt < NKT; ++kt) {
    int k0 = kt * 64;
    u16* kcur = (kt & 1) ? ks1 : ks0;
    u16* knxt = (kt & 1) ? ks0 : ks1;
    u16* vcur = (kt & 1) ? vs1 : vs0;
    u16* vnxt = (kt & 1) ? vs0 : vs1;
    __syncthreads();  // [T] tile-kt staging visible; prev-tile readers drained

    // stage tile kt+1 into nxt buffers; prefetch tile kt+2
    if (kt < NKT - 1) {
#pragma unroll
      for (int it = 0; it < 2; ++it) {
        *(u32x4*)&knxt[(it * 32 + kr) * QSTR + kc] = kreg[it];
        *(u32x4*)&vnxt[(it * 64 + vr) * VSTR + vc] = vreg[it];
      }
      int kn = (kt + 2 < NKT) ? (kt + 2) * 64 : (NKT - 1) * 64;
#pragma unroll
      for (int it = 0; it < 2; ++it) {
        kreg[it] = *(const u32x4*)&gkb[(size_t)(kn + it * 32 + kr) * 128 + kc];
        vreg[it] = *(const u32x4*)&gvb[(size_t)(it * 64 + vr) * T_ + kn + vc];
      }
    }

    // S'[k][q] = mfma(K, Q): rows = this wave's 32 k's, cols = its 32 q's
    f32x16 sacc;
#pragma unroll
    for (int i = 0; i < 16; ++i) sacc[i] = 0.f;
    {
      const u16* krow = &kcur[(kh * 32 + l31) * QSTR + lh8];
#pragma unroll
      for (int s = 0; s < 8; ++s) {
        bf16x8 kf = ldfrag(krow + s * 16);
        sacc = __builtin_amdgcn_mfma_f32_32x32x16_bf16(kf, qfrag[s], sacc, 0, 0, 0);
      }
    }

    // diagonal adjust: row = k-local, col = q-local
    if (k0 + kh * 32 == q0 + qt * 32) {
#pragma unroll
      for (int r = 0; r < 16; ++r) {
        int row = (r & 3) + 8 * (r >> 2) + 4 * h;
        if (row == l31) sacc[r] *= 0.97790291f;  // 1 - 1/sqrt(2048)
      }
    }

    // w = exp(exp(s)); den (one q per lane); pack + half-wave exchange
    float w[16];
#pragma unroll
    for (int r = 0; r < 16; ++r) w[r] = __expf(__expf(sacc[r]));
#pragma unroll
    for (int r = 0; r < 16; ++r) den += w[r];
    u32 p00 = pk2(w[0], w[1]),  p01 = pk2(w[2], w[3]);
    u32 p10 = pk2(w[4], w[5]),  p11 = pk2(w[6], w[7]);
    u32 p20 = pk2(w[8], w[9]),  p21 = pk2(w[10], w[11]);
    u32 p30 = pk2(w[12], w[13]), p31 = pk2(w[14], w[15]);
    u32 e0 = __shfl_xor(h ? p00 : p10, 32, 64);
    u32 e1 = __shfl_xor(h ? p01 : p11, 32, 64);
    u32 e2 = __shfl_xor(h ? p20 : p30, 32, 64);
    u32 e3 = __shfl_xor(h ? p21 : p31, 32, 64);
    u32x4 f0 = h ? u32x4{e0, e1, p10, p11} : u32x4{p00, p01, e0, e1};
    u32x4 f1 = h ? u32x4{e2, e3, p30, p31} : u32x4{p20, p21, e2, e3};
    bf16x8 bw0 = __builtin_bit_cast(bf16x8, f0);
    bf16x8 bw1 = __builtin_bit_cast(bf16x8, f1);

    // PV partials over this wave's 32 k's, all 128 m
#pragma unroll
    for (int mt = 0; mt < 4; ++mt) {
      const u16* vrow = &vcur[(mt * 32 + l31) * VSTR + kh * 32 + lh8];
      bf16x8 vf0 = ldfrag(vrow);
      bf16x8 vf1 = ldfrag(vrow + 16);
      pacc[mt] = __builtin_amdgcn_mfma_f32_32x32x16_bf16(vf0, bw0, pacc[mt], 0, 0, 0);
      pacc[mt] = __builtin_amdgcn_mfma_f32_32x32x16_bf16(vf1, bw1, pacc[mt], 0, 0, 0);
    }
  }

  // per-q denominator for this k-half (lane q = l31, both h halves summed)
  float dq = den + __shfl_xor(den, 32, 64);

  __syncthreads();  // [E1] all PV reads of ks/vs done -> pbuf alias safe

  if (kh == 1) {
#pragma unroll
    for (int mt = 0; mt < 4; ++mt) {
      float* pb = &pbuf[((size_t)(qt * 4 + mt) * 64 + lane) * 16];
#pragma unroll
      for (int g = 0; g < 4; ++g) {
        f32x4 v = {pacc[mt][4 * g], pacc[mt][4 * g + 1],
                   pacc[mt][4 * g + 2], pacc[mt][4 * g + 3]};
        *(f32x4*)(pb + 4 * g) = v;
      }
    }
    if (lane < 32) dls[qt * 32 + lane] = dq;
  }
  __syncthreads();  // [E2]

  if (kh == 0) {
    float rden = 1.f / (dq + dls[qt * 32 + l31]);
#pragma unroll
    for (int mt = 0; mt < 4; ++mt) {
      const float* pb = &pbuf[((size_t)(qt * 4 + mt) * 64 + lane) * 16];
#pragma unroll
      for (int g = 0; g < 4; ++g) {
        f32x4 t = *(const f32x4*)(pb + 4 * g);
        float v0 = (pacc[mt][4 * g + 0] + t[0]) * rden;
        float v1 = (pacc[mt][4 * g + 1] + t[1]) * rden;
        float v2 = (pacc[mt][4 * g + 2] + t[2]) * rden;
        float v3 = (pacc[mt][4 * g + 3] + t[3]) * rden;
        int m0 = mt * 32 + 8 * g + 4 * h;
        u32x2 wp = {pk2(v0, v1), pk2(v2, v3)};
        *(u32x2*)&qsw[(qt * 32 + l31) * QSTR + m0] = wp;
      }
    }
  }
  __syncthreads();  // [E3] P^T visible

  // o-MLP epilogue: wave wv -> o-tile (wv&3), q-tiles {2*kh, 2*kh+1}
  bf16x8 aofr[8];
  {
    const u16* ap = Ao_bf + ((wv & 3) * 32 + l31) * 128 + lh8;
#pragma unroll
    for (int s = 0; s < 8; ++s) aofr[s] = ldfrag(ap + 16 * s);
  }
#pragma unroll
  for (int j = 0; j < 2; ++j) {
    int qt2 = kh * 2 + j;
    bf16x8 pfr[8];
    const u16* pp = &qsw[(qt2 * 32 + l31) * QSTR + lh8];
#pragma unroll
    for (int s = 0; s < 8; ++s) pfr[s] = ldfrag(pp + 16 * s);
    f32x16 oacc;
#pragma unroll
    for (int r = 0; r < 16; ++r) oacc[r] = 0.f;
#pragma unroll
    for (int s = 0; s < 8; ++s)
      oacc = __builtin_amdgcn_mfma_f32_32x32x16_bf16(aofr[s], pfr[s], oacc, 0, 0, 0);
#pragma unroll
    for (int r = 0; r < 16; ++r) {
      int orow = (wv & 3) * 32 + (r & 3) + 8 * (r >> 2) + 4 * h;
      float v = oacc[r] + co[orow];
      v = v > 0.f ? v : 0.01f * v;
      out[((size_t)(b * M_ + orow)) * TOUT_ + q0 + qt2 * 32 + l31] = v;
    }
  }

  // rep_ex tail
  if (blockIdx.x == 0 && tid < 128) {
    float acc = co[tid];
    const float* mv = meanv + b * 128;
    for (int m = 0; m < 128; ++m) acc = fmaf(Aofp[tid * 128 + m], mv[m], acc);
    acc = acc > 0.f ? acc : 0.01f * acc;
    out[((size_t)(b * M_ + tid)) * TOUT_ + 2048] = acc;
  }
}

// ---------------------------------------------------------------------------
extern "C" void kernel_launch(void* const* d_in, const int* in_sizes, int n_in,
                              void* d_out, int out_size, void* d_ws, size_t ws_size,
                              hipStream_t stream) {
  (void)in_sizes; (void)n_in; (void)out_size; (void)ws_size;
  const float* pattern = (const float*)d_in[0];
  const float* value   = (const float*)d_in[1];
  const float* Wq1 = (const float*)d_in[3];
  const float* bq1 = (const float*)d_in[4];
  const float* Wq2 = (const float*)d_in[5];
  const float* bq2 = (const float*)d_in[6];
  const float* Wk1 = (const float*)d_in[7];
  const float* bk1 = (const float*)d_in[8];
  const float* Wk2 = (const float*)d_in[9];
  const float* bk2 = (const float*)d_in[10];
  const float* Wo1 = (const float*)d_in[11];
  const float* bo1 = (const float*)d_in[12];
  const float* Wo2 = (const float*)d_in[13];
  const float* bo2 = (const float*)d_in[14];

  float* ws     = (float*)d_ws;
  float* A      = ws + A_OFF;
  float* c      = ws + C_OFF;
  float* meanv  = ws + MEAN_OFF;
  u16*   Aqk_bf = (u16*)(ws + AQKBF_OFF);
  u16*   Ao_bf  = (u16*)(ws + AOBF_OFF);
  u16*   qT     = (u16*)(ws + QT_OFF);
  u16*   kT     = (u16*)(ws + KT_OFF);
  u16*   vB     = (u16*)(ws + VB_OFF);
  float* out    = (float*)d_out;

  fuse_weights_all<<<384, 128, 0, stream>>>(
      Wq1, bq1, Wq2, bq2, Wk1, bk1, Wk2, bk2, Wo1, bo1, Wo2, bo2,
      A, c, Aqk_bf, Ao_bf);

  prep_kernel<<<512 + B_ * M_, 256, 0, stream>>>(
      pattern, Aqk_bf, c, qT, kT, value, vB, meanv);

  // LDS: qsw 34816 + ks dbuf 34816 + vs dbuf 36864 + dls 512 = 107008 B
  size_t lds_bytes = (size_t)(128 * QSTR + 2 * 64 * QSTR + 2 * 128 * VSTR) * 2
                   + 128 * 4;
  attn_mfma_kernel<<<dim3(T_ / 128, B_), 512, lds_bytes, stream>>>(
      qT, kT, vB, Ao_bf, c + 256, A, meanv, out);
}